// Round 5
// baseline (3312.733 us; speedup 1.0000x reference)
//
#include <hip/hip_runtime.h>
#include <math.h>

// ===========================================================================
// ImplicitMap fExtractor on MFMA (fp16 split scheme), round 5.
// State per point = 5 fp16 planes: [x_hi, x_lo, g1, g2, g3].
//   x as exact fp16 hi+lo pair -> 3-pass MFMA == fp32-accurate z.
//   g planes single-pass fp16.
// Round-5 changes (schedule/shape only, math identical):
//   * 64m x 256o block, 8 waves (512 thr), wave tile 32m x 64o
//   * 3-stage LDS ring (156 KB, 1 block/CU): prefetch depth = 2 full
//     iterations (~3000 cyc) >> HBM latency -> vmcnt stalls vanish
//   * halves B L2-refetch per MFMA (was the tightest bandwidth pipe)
//   * scalar (SGPR) staging addresses via readfirstlane; per-wave counted
//     vmcnt with uneven 7/6 chunk assignment
// ===========================================================================

typedef unsigned short u16;
typedef _Float16 f16;
typedef f16   f16x8  __attribute__((ext_vector_type(8)));
typedef float f32x16 __attribute__((ext_vector_type(16)));

__device__ __forceinline__ u16   f2h(float x){ return __builtin_bit_cast(u16, (f16)x); }
__device__ __forceinline__ float h2f(u16 b){ return (float)__builtin_bit_cast(f16, b); }

__device__ __forceinline__ void glld16(const void* g, void* l){
  __builtin_amdgcn_global_load_lds(
      (const __attribute__((address_space(1))) unsigned*)g,
      (__attribute__((address_space(3))) unsigned*)l, 16, 0, 0);
}

template<int N> __device__ __forceinline__ void wait_vmcnt(){
  static_assert(N==0||N==5||N==6||N==7||N==10||N==12||N==14, "bad vmcnt");
  if constexpr (N == 0)  asm volatile("s_waitcnt vmcnt(0)"  ::: "memory");
  if constexpr (N == 5)  asm volatile("s_waitcnt vmcnt(5)"  ::: "memory");
  if constexpr (N == 6)  asm volatile("s_waitcnt vmcnt(6)"  ::: "memory");
  if constexpr (N == 7)  asm volatile("s_waitcnt vmcnt(7)"  ::: "memory");
  if constexpr (N == 10) asm volatile("s_waitcnt vmcnt(10)" ::: "memory");
  if constexpr (N == 12) asm volatile("s_waitcnt vmcnt(12)" ::: "memory");
  if constexpr (N == 14) asm volatile("s_waitcnt vmcnt(14)" ::: "memory");
}

// NP = input planes: 2 for layer 1 (x hi/lo), 5 for mid layers.
template<int NP>
__global__ __launch_bounds__(512, 2)
void fused_layer(const u16* __restrict__ Sin, long long psIn, int kpad,
                 u16* __restrict__ Sout, long long psOut, int opitch,
                 const u16* __restrict__ Wh, const u16* __restrict__ Wl,
                 const float* __restrict__ bias, const float* __restrict__ Wfirst,
                 int cout, int cinFirst)
{
  constexpr bool FIRST = (NP == 2);
  constexpr int ACH   = NP * 4;            // A staging chunks (1 KB each)
  constexpr int CH    = ACH + 32;          // + B chunks
  constexpr int ABUFE = NP * 2048;         // A region elems per buffer
  constexpr int BUFE  = ABUFE + 16384;     // buffer elems (A + B)
  constexpr int CBASE = CH / 8;            // chunks per wave (floor)
  constexpr int CREM  = CH % 8;            // waves with one extra chunk
  constexpr int MAXC  = CBASE + (CREM ? 1 : 0);

  __shared__ __align__(16) u16 lds[3 * BUFE];

  // ---- XCD swizzle: contiguous m-band per XCD, o fastest inside ----
  int bx = blockIdx.x, by = blockIdx.y;
  {
    const int gx = gridDim.x, gy = gridDim.y;
    const int nwg = gx * gy;
    const int d   = by * gx + bx;
    if ((nwg & 7) == 0){
      const int q = nwg >> 3;
      const int t = (d & 7) * q + (d >> 3);
      by = t % gy;
      bx = t / gy;
    }
  }

  const int tid  = threadIdx.x;
  const int ws   = __builtin_amdgcn_readfirstlane(tid >> 6);  // wave id (SGPR)
  const int lane = tid & 63;
  const int lrow = lane & 31;
  const int lhalf= lane >> 5;
  const int mh   = ws & 1;        // wave m-half (32 rows)
  const int oq   = ws >> 1;       // wave o-quarter (64 cols)
  const int m0   = bx * 64;
  const int o0   = by * 256;
  const bool act = (o0 + oq * 64) < opitch;   // wave has real output cols

  // ---- per-wave staging chunk table (scalar bases; vLane is the only VGPR)
  const int cnt = (CREM && ws < CREM) ? CBASE + 1 : CBASE;
  const int c0  = (CREM && ws < CREM) ? ws * (CBASE + 1)
                                      : CREM * (CBASE + 1) + (ws - CREM) * CBASE;
  const u16* gptr[MAXC];
  int ldsOffE[MAXC];
  #pragma unroll
  for (int j = 0; j < MAXC; ++j){
    const int c = c0 + ((j < cnt) ? j : 0);
    if (c < ACH){
      const int p = c >> 2, kq = c & 3;
      gptr[j]    = Sin + (long long)p * psIn + (long long)m0 * kpad + kq * 8;
      ldsOffE[j] = p * 2048 + kq * 512;
    } else {
      const int b = c - ACH;
      const int h = b >> 4, kq = (b >> 2) & 3, gg = b & 3;
      gptr[j]    = (h ? Wl : Wh) + (long long)(o0 + gg * 64) * kpad + kq * 8;
      ldsOffE[j] = ABUFE + h * 8192 + kq * 2048 + gg * 512;
    }
  }
  const int vLane = lane * kpad;   // per-lane element offset (rows stride)

  f32x16 zinit = {};
  f32x16 accx[2];
  f32x16 accg[FIRST ? 1 : 3][2];
  accx[0] = zinit; accx[1] = zinit;
  if constexpr (!FIRST){
    #pragma unroll
    for (int j = 0; j < 3; ++j){ accg[j][0] = zinit; accg[j][1] = zinit; }
  }

  auto stage = [&](int bufE, int ktE){
    #pragma unroll
    for (int j = 0; j < MAXC; ++j)
      if (j < cnt)
        glld16(gptr[j] + vLane + ktE, &lds[bufE + ldsOffE[j]]);
  };

  auto compute = [&](int bufE){
    if (!act) return;
    __builtin_amdgcn_s_setprio(1);
    #pragma unroll
    for (int s = 0; s < 2; ++s){
      const int kq = s * 2 + lhalf;
      const int aoff = bufE + kq * 512 + (mh * 32 + lrow) * 8;
      f16x8 a[NP];
      #pragma unroll
      for (int p = 0; p < NP; ++p)
        a[p] = *(const f16x8*)&lds[aoff + p * 2048];
      #pragma unroll
      for (int f = 0; f < 2; ++f){
        const int row  = oq * 64 + f * 32 + lrow;
        const int boff = bufE + ABUFE + kq * 2048 + row * 8;
        f16x8 bh = *(const f16x8*)&lds[boff];
        f16x8 bl = *(const f16x8*)&lds[boff + 8192];
        accx[f] = __builtin_amdgcn_mfma_f32_32x32x16_f16(a[0], bh, accx[f], 0,0,0);
        accx[f] = __builtin_amdgcn_mfma_f32_32x32x16_f16(a[1], bh, accx[f], 0,0,0);
        accx[f] = __builtin_amdgcn_mfma_f32_32x32x16_f16(a[0], bl, accx[f], 0,0,0);
        if constexpr (!FIRST){
          #pragma unroll
          for (int j = 0; j < 3; ++j)
            accg[j][f] = __builtin_amdgcn_mfma_f32_32x32x16_f16(a[2+j], bh, accg[j][f], 0,0,0);
        }
      }
    }
    __builtin_amdgcn_s_setprio(0);
  };

  // ---- 3-stage ring, counted vmcnt (loads span 2 full iterations) ----
  const int nk = kpad >> 5;
  stage(0, 0);
  stage(BUFE, 32);
  stage(2 * BUFE, 64);
  int bufE = 0;
  for (int t = 0; t < nk; ++t){
    const int ahead = nk - 1 - t;   // stages issued beyond t
    if (ahead >= 2){
      if (CREM && cnt == CBASE + 1) wait_vmcnt<2*CBASE + 2>();
      else                          wait_vmcnt<2*CBASE>();
    } else if (ahead == 1){
      if (CREM && cnt == CBASE + 1) wait_vmcnt<CBASE + 1>();
      else                          wait_vmcnt<CBASE>();
    } else {
      wait_vmcnt<0>();
    }
    __builtin_amdgcn_s_barrier();
    compute(bufE);
    asm volatile("s_waitcnt lgkmcnt(0)" ::: "memory");
    __builtin_amdgcn_s_barrier();
    if (t + 3 < nk) stage(bufE, (t + 3) * 32);
    bufE += BUFE; if (bufE == 3 * BUFE) bufE = 0;
  }

  if (!act) return;
  // ---- epilogue: D layout col=lane&31, row=(r&3)+8*(r>>2)+4*(lane>>5) ----
  const int mb = m0 + mh * 32;
  #pragma unroll
  for (int f = 0; f < 2; ++f){
    const int o = o0 + oq * 64 + f * 32 + lrow;
    const float bo = (o < cout) ? bias[o] : 0.f;
    float w0 = 0.f, w1 = 0.f, w2 = 0.f;
    if constexpr (FIRST){
      if (o < cout){
        w0 = Wfirst[(long long)o * cinFirst + 0];
        w1 = Wfirst[(long long)o * cinFirst + 1];
        w2 = Wfirst[(long long)o * cinFirst + 2];
      }
    }
    #pragma unroll
    for (int r = 0; r < 16; ++r){
      const int m = mb + (r & 3) + ((r >> 2) << 3) + (lhalf << 2);
      const float z    = accx[f][r] + bo;
      const float gate = 1.f / (1.f + expf(-100.f * z));
      const float sp   = fmaxf(z, 0.f) + 0.01f * log1pf(expf(-100.f * fabsf(z)));
      const long long idx = (long long)m * opitch + o;
      const u16 xh = f2h(sp);
      Sout[idx]          = xh;
      Sout[psOut + idx]  = f2h(sp - h2f(xh));
      if constexpr (FIRST){
        Sout[2*psOut + idx] = f2h(gate * w0);
        Sout[3*psOut + idx] = f2h(gate * w1);
        Sout[4*psOut + idx] = f2h(gate * w2);
      } else {
        Sout[2*psOut + idx] = f2h(gate * accg[0][f][r]);
        Sout[3*psOut + idx] = f2h(gate * accg[1][f][r]);
        Sout[4*psOut + idx] = f2h(gate * accg[2][f][r]);
      }
    }
  }
}

// Final 896->1: z (no act) -> out1; g = W@g (no gate) -> out2.
__global__ __launch_bounds__(256)
void final_layer(const u16* __restrict__ Sin, long long ps, int kpad,
                 const float* __restrict__ W, const float* __restrict__ bias,
                 float* __restrict__ out1, float* __restrict__ out2,
                 int cin, int mBase)
{
  const int lane = threadIdx.x & 63;
  const int wv   = threadIdx.x >> 6;
  const int m = blockIdx.x * 4 + wv;
  const u16* row = Sin + (long long)m * kpad;
  float s0=0.f, s1=0.f, s2=0.f, s3=0.f;
  for (int c = lane; c < cin; c += 64){
    const float w = W[c];
    s0 += (h2f(row[c]) + h2f(row[ps + c])) * w;
    s1 += h2f(row[2*ps + c]) * w;
    s2 += h2f(row[3*ps + c]) * w;
    s3 += h2f(row[4*ps + c]) * w;
  }
  #pragma unroll
  for (int off = 32; off > 0; off >>= 1){
    s0 += __shfl_xor(s0, off); s1 += __shfl_xor(s1, off);
    s2 += __shfl_xor(s2, off); s3 += __shfl_xor(s3, off);
  }
  if (lane == 0){
    out1[mBase + m] = s0 + bias[0];
    float* g = out2 + (long long)(mBase + m) * 3;
    g[0] = s1; g[1] = s2; g[2] = s3;
  }
}

// out3 = input_con (fp32), plus padded fp16 hi/lo copy for the layer-1 GEMM.
__global__ void prep_input(const float* __restrict__ input,
                           const float* __restrict__ latent,
                           float* __restrict__ out3,
                           u16* __restrict__ x0, long long psX0, int N)
{
  const int m = blockIdx.x;
  const int b = m / N;
  const int c = threadIdx.x;
  if (c >= 288) return;
  float v = 0.f;
  if (c < 3) v = input[(long long)m*3 + c];
  else if (c < 259) v = latent[(long long)b*256 + (c - 3)];
  if (c < 259) out3[(long long)m*259 + c] = v;
  const u16 h = f2h(v);
  x0[(long long)m*288 + c]        = h;
  x0[psX0 + (long long)m*288 + c] = f2h(v - h2f(h));
}

// fp32 W -> zero-padded fp16 hi/lo.
__global__ void split_w(const float* __restrict__ W, u16* __restrict__ wh,
                        u16* __restrict__ wl, int cout, int cin, int kpad, int total)
{
  const int idx = blockIdx.x * 256 + threadIdx.x;
  if (idx >= total) return;
  const int o = idx / kpad, c = idx % kpad;
  const float v = (o < cout && c < cin) ? W[(long long)o*cin + c] : 0.f;
  const u16 h = f2h(v);
  wh[idx] = h;
  wl[idx] = f2h(v - h2f(h));
}

extern "C" void kernel_launch(void* const* d_in, const int* in_sizes, int n_in,
                              void* d_out, int out_size, void* d_ws, size_t ws_size,
                              hipStream_t stream)
{
  static const int CIN [12] = {259,515,512,512,576,576,768,768,768,960,960,896};
  static const int COUT[12] = {515,512,512,576,576,768,768,768,960,960,896,1};
  int OPAD[11], OP256[11], KPAD[12];
  KPAD[0] = 288;
  for (int i = 0; i < 11; ++i){
    OPAD[i]  = ((COUT[i] + 127) / 128) * 128;   // state-plane pitch
    OP256[i] = ((COUT[i] + 255) / 256) * 256;   // B storage rows (block o-width)
    KPAD[i+1] = OPAD[i];
  }

  const float* input  = (const float*)d_in[0];
  const float* latent = (const float*)d_in[1];
  auto Wp = [&](int i){ return (const float*)d_in[2 + 2*i]; };
  auto Bp = [&](int i){ return (const float*)d_in[3 + 2*i]; };

  const int Bn = in_sizes[1] / 256;
  const int Nn = in_sizes[0] / (3 * Bn);
  const int M  = Bn * Nn;                       // 16384

  float* out1 = (float*)d_out;                  // (B,1,N)
  float* out2 = out1 + M;                       // (B,N,1,3)
  float* out3 = out2 + (size_t)M * 3;           // input_con (B,N,259) fp32

  // ---- ws carve-up ----
  char* wsp = (char*)d_ws;
  u16 *WH[11], *WL[11];
  for (int i = 0; i < 11; ++i){
    const size_t sz = (size_t)OP256[i] * KPAD[i] * 2;  // bytes per array
    WH[i] = (u16*)wsp; wsp += sz;
    WL[i] = (u16*)wsp; wsp += sz;
  }
  u16* x0 = (u16*)wsp;
  const long long psX0 = (long long)M * 288;
  wsp += (size_t)2 * psX0 * 2;

  const size_t used = (size_t)(wsp - (char*)d_ws);
  const size_t remain = (ws_size > used) ? (ws_size - used) : 0;
  const size_t perPoint = (size_t)2 * 5 * 1024 * 2;   // 20480 B/pt (2 bufs)
  long long pc = (long long)(remain / perPoint);
  pc &= ~63LL;
  // Cap at 8192 points: layer in+out state stays L3-resident.
  int Pc = (int)((pc < 8192LL) ? pc : 8192LL);
  if (Pc > M) Pc = M;
  if (Pc < 64) Pc = 64;
  u16* bufA = (u16*)wsp;
  u16* bufB = bufA + (size_t)5 * Pc * 1024;

  // ---- prologue: input_con + x0 split, weight splits ----
  prep_input<<<M, 320, 0, stream>>>(input, latent, out3, x0, psX0, Nn);
  for (int i = 0; i < 11; ++i){
    const int total = OP256[i] * KPAD[i];
    split_w<<<(total + 255)/256, 256, 0, stream>>>(
        Wp(i), WH[i], WL[i], COUT[i], CIN[i], KPAD[i], total);
  }

  // ---- layer chain (chunked over points; chunks are L3-resident) ----
  for (int cm0 = 0; cm0 < M; cm0 += Pc){
    const int Mc = (M - cm0 < Pc) ? (M - cm0) : Pc;

    {
      dim3 g(Mc/64, OP256[0]/256);
      fused_layer<2><<<g, 512, 0, stream>>>(
          x0 + (long long)cm0 * 288, psX0, 288,
          bufA, (long long)Pc * OPAD[0], OPAD[0],
          WH[0], WL[0], Bp(0), Wp(0), COUT[0], CIN[0]);
    }
    u16* src = bufA;
    u16* dst = bufB;
    for (int i = 1; i <= 10; ++i){
      dim3 g(Mc/64, OP256[i]/256);
      fused_layer<5><<<g, 512, 0, stream>>>(
          src, (long long)Pc * KPAD[i], KPAD[i],
          dst, (long long)Pc * OPAD[i], OPAD[i],
          WH[i], WL[i], Bp(i), nullptr, COUT[i], 0);
      u16* t = src; src = dst; dst = t;
    }
    final_layer<<<Mc/4, 256, 0, stream>>>(
        src, (long long)Pc * KPAD[11], KPAD[11],
        Wp(11), Bp(11), out1, out2, CIN[11], cm0);
  }
}

// Round 6
// 2645.689 us; speedup vs baseline: 1.2521x; 1.2521x over previous
//
#include <hip/hip_runtime.h>
#include <math.h>

// ===========================================================================
// ImplicitMap fExtractor on MFMA (fp16 split scheme), round 6.
// State per point = 5 fp16 planes: [x_hi, x_lo, g1, g2, g3].
//   x as exact fp16 hi+lo pair -> 3-pass MFMA == fp32-accurate z.
//   g planes single-pass fp16.
// Round-6 changes vs R4 (geometry/pipeline IDENTICAL to R4 = best so far):
//   * Pc cap removed: full M=16384 per dispatch -> grid tails become
//     near-integral multiples of the 512 resident-block slots (was ~1.3x
//     round-quantization waste), and 11 instead of 22 layer dispatches.
//   * KPAD 32-aligned instead of 128-aligned (515->544 not 640): -8% MFMA
//     and staging work. Bit-exact: pad x-cols hit zero-padded W columns.
//   * Stores masked to the (smaller) 32-aligned output pitch.
// ===========================================================================

typedef unsigned short u16;
typedef _Float16 f16;
typedef f16   f16x8  __attribute__((ext_vector_type(8)));
typedef float f32x16 __attribute__((ext_vector_type(16)));

__device__ __forceinline__ u16   f2h(float x){ return __builtin_bit_cast(u16, (f16)x); }
__device__ __forceinline__ float h2f(u16 b){ return (float)__builtin_bit_cast(f16, b); }

__device__ __forceinline__ void glld16(const void* g, void* l){
  __builtin_amdgcn_global_load_lds(
      (const __attribute__((address_space(1))) unsigned*)g,
      (__attribute__((address_space(3))) unsigned*)l, 16, 0, 0);
}

template<int N> __device__ __forceinline__ void wait_vmcnt(){
  static_assert(N == 0 || N == 6 || N == 9, "unsupported vmcnt literal");
  if constexpr (N == 0) asm volatile("s_waitcnt vmcnt(0)" ::: "memory");
  if constexpr (N == 6) asm volatile("s_waitcnt vmcnt(6)" ::: "memory");
  if constexpr (N == 9) asm volatile("s_waitcnt vmcnt(9)" ::: "memory");
}

// NP = input planes staged: 2 for layer 1 (x hi/lo), 5 for mid layers.
template<int NP>
__global__ __launch_bounds__(256, 2)
void fused_layer(const u16* __restrict__ Sin, long long psIn, int kpad,
                 u16* __restrict__ Sout, long long psOut, int opitch,
                 const u16* __restrict__ Wh, const u16* __restrict__ Wl,
                 const float* __restrict__ bias, const float* __restrict__ Wfirst,
                 int cout, int cinFirst)
{
  constexpr bool FIRST = (NP == 2);
  constexpr int  S     = NP + 4;    // global_load_lds per wave per stage
  // K-outer-major: [buf][tile][kq(8-elem block)][row][8]; 16B cell per (kq,row)
  __shared__ u16 As[2][NP][4][64][8];
  __shared__ u16 Bs[2][2][4][128][8];

  // ---- XCD swizzle: contiguous m-band per XCD, o fastest inside ----
  int bx = blockIdx.x, by = blockIdx.y;
  {
    const int gx = gridDim.x, gy = gridDim.y;
    const int nwg = gx * gy;
    const int d   = by * gx + bx;        // hw dispatch order (x fastest)
    if ((nwg & 7) == 0){
      const int q = nwg >> 3;
      const int t = (d & 7) * q + (d >> 3);
      by = t % gy;                       // o fastest
      bx = t / gy;                       // contiguous m-band per XCD
    }
  }

  const int tid   = threadIdx.x;
  const int w     = tid >> 6;     // wave id: stages kq-block w of every tile
  const int lane  = tid & 63;
  const int lrow  = lane & 31;
  const int lhalf = lane >> 5;
  const int mh    = w >> 1;       // wave's m-half (32 rows)
  const int oh    = w & 1;        // wave's o-half (64 cols)
  const int m0    = bx * 64;
  const int o0    = by * 128;

  f32x16 zinit = {};
  f32x16 accx[2];
  f32x16 accg[FIRST ? 1 : 3][2];
  accx[0] = zinit; accx[1] = zinit;
  if constexpr (!FIRST){
    #pragma unroll
    for (int j = 0; j < 3; ++j){ accg[j][0] = zinit; accg[j][1] = zinit; }
  }

  // per-lane global sources (lane -> LDS base + lane*16 by glld semantics)
  const u16* aSrc[NP];
  #pragma unroll
  for (int p = 0; p < NP; ++p)
    aSrc[p] = Sin + (long long)p * psIn + (long long)(m0 + lane) * kpad + w * 8;
  const u16* bSrc[2][2];
  #pragma unroll
  for (int h = 0; h < 2; ++h){
    const u16* Wx = h ? Wl : Wh;
    #pragma unroll
    for (int hf = 0; hf < 2; ++hf)
      bSrc[h][hf] = Wx + (long long)(o0 + hf*64 + lane) * kpad + w * 8;
  }

  auto stage = [&](int buf, int kElem){
    #pragma unroll
    for (int p = 0; p < NP; ++p)
      glld16(aSrc[p] + kElem, &As[buf][p][w][0][0]);
    #pragma unroll
    for (int h = 0; h < 2; ++h)
      #pragma unroll
      for (int hf = 0; hf < 2; ++hf)
        glld16(bSrc[h][hf] + kElem, &Bs[buf][h][w][hf*64][0]);
  };

  auto compute = [&](int buf){
    __builtin_amdgcn_s_setprio(1);
    #pragma unroll
    for (int s = 0; s < 2; ++s){
      const int kq = s*2 + lhalf;        // A/B frag: k = 8*(lane>>5)+e
      f16x8 a[NP];
      #pragma unroll
      for (int p = 0; p < NP; ++p)
        a[p] = *(const f16x8*)&As[buf][p][kq][mh*32 + lrow][0];
      #pragma unroll
      for (int f = 0; f < 2; ++f){
        const int oc = oh*64 + f*32 + lrow;
        f16x8 bh = *(const f16x8*)&Bs[buf][0][kq][oc][0];
        f16x8 bl = *(const f16x8*)&Bs[buf][1][kq][oc][0];
        // x plane: 3-pass split (xh*Wh + xl*Wh + xh*Wl), ~fp32 accurate
        accx[f] = __builtin_amdgcn_mfma_f32_32x32x16_f16(a[0], bh, accx[f], 0,0,0);
        accx[f] = __builtin_amdgcn_mfma_f32_32x32x16_f16(a[1], bh, accx[f], 0,0,0);
        accx[f] = __builtin_amdgcn_mfma_f32_32x32x16_f16(a[0], bl, accx[f], 0,0,0);
        if constexpr (!FIRST){
          #pragma unroll
          for (int j = 0; j < 3; ++j)   // g planes: single pass
            accg[j][f] = __builtin_amdgcn_mfma_f32_32x32x16_f16(a[2+j], bh, accg[j][f], 0,0,0);
        }
      }
    }
    __builtin_amdgcn_s_setprio(0);
  };

  // ---- counted-vmcnt double-buffered K loop ----
  const int nk = kpad >> 5;
  stage(0, 0);
  stage(1, 32);
  int cur = 0;
  for (int t = 0; t < nk - 1; ++t){
    wait_vmcnt<S>();                 // tile t landed (t+1 still in flight)
    __builtin_amdgcn_s_barrier();
    compute(cur);
    asm volatile("s_waitcnt lgkmcnt(0)" ::: "memory");  // my LDS reads returned
    __builtin_amdgcn_s_barrier();    // everyone done reading buf[cur]
    if (t + 2 < nk) stage(cur, (t + 2) * 32);
    cur ^= 1;
  }
  wait_vmcnt<0>();
  __builtin_amdgcn_s_barrier();
  compute(cur);

  // ---- epilogue: D layout col=lane&31, row=(r&3)+8*(r>>2)+4*(lane>>5) ----
  const int mb = m0 + mh*32;
  #pragma unroll
  for (int f = 0; f < 2; ++f){
    const int o = o0 + oh*64 + f*32 + lrow;
    if (o >= opitch) continue;       // 32-aligned output pitch (stores masked)
    const float bo = (o < cout) ? bias[o] : 0.f;
    float w0 = 0.f, w1 = 0.f, w2 = 0.f;
    if constexpr (FIRST){
      if (o < cout){
        w0 = Wfirst[(long long)o*cinFirst + 0];
        w1 = Wfirst[(long long)o*cinFirst + 1];
        w2 = Wfirst[(long long)o*cinFirst + 2];
      }
    }
    #pragma unroll
    for (int r = 0; r < 16; ++r){
      const int m = mb + (r & 3) + ((r >> 2) << 3) + (lhalf << 2);
      const float z    = accx[f][r] + bo;
      const float gate = 1.f / (1.f + expf(-100.f * z));
      const float sp   = fmaxf(z, 0.f) + 0.01f * log1pf(expf(-100.f * fabsf(z)));
      const long long idx = (long long)m * opitch + o;
      const u16 xh = f2h(sp);
      Sout[idx]          = xh;
      Sout[psOut + idx]  = f2h(sp - h2f(xh));
      if constexpr (FIRST){
        Sout[2*psOut + idx] = f2h(gate * w0);
        Sout[3*psOut + idx] = f2h(gate * w1);
        Sout[4*psOut + idx] = f2h(gate * w2);
      } else {
        Sout[2*psOut + idx] = f2h(gate * accg[0][f][r]);
        Sout[3*psOut + idx] = f2h(gate * accg[1][f][r]);
        Sout[4*psOut + idx] = f2h(gate * accg[2][f][r]);
      }
    }
  }
}

// Final 896->1: z (no act) -> out1; g = W@g (no gate) -> out2.
__global__ __launch_bounds__(256)
void final_layer(const u16* __restrict__ Sin, long long ps, int kpad,
                 const float* __restrict__ W, const float* __restrict__ bias,
                 float* __restrict__ out1, float* __restrict__ out2,
                 int cin, int mBase)
{
  const int lane = threadIdx.x & 63;
  const int wv   = threadIdx.x >> 6;
  const int m = blockIdx.x * 4 + wv;
  const u16* row = Sin + (long long)m * kpad;
  float s0=0.f, s1=0.f, s2=0.f, s3=0.f;
  for (int c = lane; c < cin; c += 64){
    const float w = W[c];
    s0 += (h2f(row[c]) + h2f(row[ps + c])) * w;
    s1 += h2f(row[2*ps + c]) * w;
    s2 += h2f(row[3*ps + c]) * w;
    s3 += h2f(row[4*ps + c]) * w;
  }
  #pragma unroll
  for (int off = 32; off > 0; off >>= 1){
    s0 += __shfl_xor(s0, off); s1 += __shfl_xor(s1, off);
    s2 += __shfl_xor(s2, off); s3 += __shfl_xor(s3, off);
  }
  if (lane == 0){
    out1[mBase + m] = s0 + bias[0];
    float* g = out2 + (long long)(mBase + m) * 3;
    g[0] = s1; g[1] = s2; g[2] = s3;
  }
}

// out3 = input_con (fp32), plus padded fp16 hi/lo copy for the layer-1 GEMM.
__global__ void prep_input(const float* __restrict__ input,
                           const float* __restrict__ latent,
                           float* __restrict__ out3,
                           u16* __restrict__ x0, long long psX0, int N)
{
  const int m = blockIdx.x;
  const int b = m / N;
  const int c = threadIdx.x;
  if (c >= 288) return;
  float v = 0.f;
  if (c < 3) v = input[(long long)m*3 + c];
  else if (c < 259) v = latent[(long long)b*256 + (c - 3)];
  if (c < 259) out3[(long long)m*259 + c] = v;
  const u16 h = f2h(v);
  x0[(long long)m*288 + c]        = h;
  x0[psX0 + (long long)m*288 + c] = f2h(v - h2f(h));
}

// fp32 W -> zero-padded fp16 hi/lo.
__global__ void split_w(const float* __restrict__ W, u16* __restrict__ wh,
                        u16* __restrict__ wl, int cout, int cin, int kpad, int total)
{
  const int idx = blockIdx.x * 256 + threadIdx.x;
  if (idx >= total) return;
  const int o = idx / kpad, c = idx % kpad;
  const float v = (o < cout && c < cin) ? W[(long long)o*cin + c] : 0.f;
  const u16 h = f2h(v);
  wh[idx] = h;
  wl[idx] = f2h(v - h2f(h));
}

extern "C" void kernel_launch(void* const* d_in, const int* in_sizes, int n_in,
                              void* d_out, int out_size, void* d_ws, size_t ws_size,
                              hipStream_t stream)
{
  static const int CIN [12] = {259,515,512,512,576,576,768,768,768,960,960,896};
  static const int COUT[12] = {515,512,512,576,576,768,768,768,960,960,896,1};
  int NY[11], ROWS[11], KPAD[12];
  KPAD[0] = 288;
  for (int i = 0; i < 11; ++i){
    NY[i]    = (COUT[i] + 127) / 128;          // o-tiles (block width 128)
    ROWS[i]  = NY[i] * 128;                    // weight-array rows (computed o)
    KPAD[i+1] = (COUT[i] + 31) & ~31;          // 32-aligned state pitch
  }

  const float* input  = (const float*)d_in[0];
  const float* latent = (const float*)d_in[1];
  auto Wp = [&](int i){ return (const float*)d_in[2 + 2*i]; };
  auto Bp = [&](int i){ return (const float*)d_in[3 + 2*i]; };

  const int Bn = in_sizes[1] / 256;
  const int Nn = in_sizes[0] / (3 * Bn);
  const int M  = Bn * Nn;                       // 16384

  float* out1 = (float*)d_out;                  // (B,1,N)
  float* out2 = out1 + M;                       // (B,N,1,3)
  float* out3 = out2 + (size_t)M * 3;           // input_con (B,N,259) fp32

  // ---- ws carve-up ----
  char* wsp = (char*)d_ws;
  u16 *WH[11], *WL[11];
  for (int i = 0; i < 11; ++i){
    const size_t sz = (size_t)ROWS[i] * KPAD[i] * 2;  // bytes per array
    WH[i] = (u16*)wsp; wsp += sz;
    WL[i] = (u16*)wsp; wsp += sz;
  }
  u16* x0 = (u16*)wsp;
  const long long psX0 = (long long)M * 288;
  wsp += (size_t)2 * psX0 * 2;

  const size_t used = (size_t)(wsp - (char*)d_ws);
  const size_t remain = (ws_size > used) ? (ws_size - used) : 0;
  const size_t perPoint = (size_t)2 * 5 * 960 * 2;    // 19200 B/pt (2 bufs)
  long long pc = (long long)(remain / perPoint);
  pc &= ~63LL;
  // Full M per dispatch if ws allows (tail-quantization fix); chunk otherwise.
  int Pc = (int)((pc < (long long)M) ? pc : (long long)M);
  if (Pc < 64) Pc = 64;
  u16* bufA = (u16*)wsp;
  u16* bufB = bufA + (size_t)5 * Pc * 960;

  // ---- prologue: input_con + x0 split, weight splits ----
  prep_input<<<M, 320, 0, stream>>>(input, latent, out3, x0, psX0, Nn);
  for (int i = 0; i < 11; ++i){
    const int total = ROWS[i] * KPAD[i];
    split_w<<<(total + 255)/256, 256, 0, stream>>>(
        Wp(i), WH[i], WL[i], COUT[i], CIN[i], KPAD[i], total);
  }

  // ---- layer chain ----
  for (int cm0 = 0; cm0 < M; cm0 += Pc){
    const int Mc = (M - cm0 < Pc) ? (M - cm0) : Pc;

    {
      dim3 g(Mc/64, NY[0]);
      fused_layer<2><<<g, 256, 0, stream>>>(
          x0 + (long long)cm0 * 288, psX0, 288,
          bufA, (long long)Pc * KPAD[1], KPAD[1],
          WH[0], WL[0], Bp(0), Wp(0), COUT[0], CIN[0]);
    }
    u16* src = bufA;
    u16* dst = bufB;
    for (int i = 1; i <= 10; ++i){
      dim3 g(Mc/64, NY[i]);
      fused_layer<5><<<g, 256, 0, stream>>>(
          src, (long long)Pc * KPAD[i], KPAD[i],
          dst, (long long)Pc * KPAD[i+1], KPAD[i+1],
          WH[i], WL[i], Bp(i), nullptr, COUT[i], 0);
      u16* t = src; src = dst; dst = t;
    }
    final_layer<<<Mc/4, 256, 0, stream>>>(
        src, (long long)Pc * KPAD[11], KPAD[11],
        Wp(11), Bp(11), out1, out2, CIN[11], cm0);
  }
}